// Round 6
// baseline (267.668 us; speedup 1.0000x reference)
//
#include <hip/hip_runtime.h>
#include <stdint.h>

typedef unsigned short u16;
typedef unsigned int u32;
typedef __bf16 bf16x8 __attribute__((ext_vector_type(8)));
typedef float f32x4 __attribute__((ext_vector_type(4)));
typedef float f32x16 __attribute__((ext_vector_type(16)));

#define BM 128
#define BN 128
#define BK 64

__device__ __forceinline__ u16 f2bf(float x) {
  union { float f; uint32_t u; } c; c.f = x;
  uint32_t r = (c.u + 0x7FFFu + ((c.u >> 16) & 1u)) >> 16;
  return (u16)r;
}

// async global->LDS, 16B per lane; LDS dest = wave-uniform base + lane*16
__device__ __forceinline__ void async_copy16(const u16* g, u16* l) {
  __builtin_amdgcn_global_load_lds(
      (const __attribute__((address_space(1))) void*)g,
      (__attribute__((address_space(3))) void*)l,
      16, 0, 0);
}

__global__ void zerofill_u16(u16* __restrict__ p) {
  long i = (long)blockIdx.x * 256 + threadIdx.x;
  p[i] = 0;
}

// ---------- fused prep: dtype self-detect + x normalize + W transnorm ------
// Every block samples the SAME first 8192 u16 of Wq: bf16 weights give
// exactly 0 exp==0xFF hits (finite values); f32 mantissa halves give ~16
// (P(0)~1e-7). Identical sample => identical per-block decision, no global
// dependency. Block 0 also publishes the flag for the PV epilogue.
// Blocks [0,nxb): normalize x (2048 elems each). Blocks [nxb,nxb+768):
// normalize+transpose the three weights (64x64 tiles).
__global__ __launch_bounds__(256)
void prep(const void* __restrict__ xs, const void* __restrict__ w0,
          const void* __restrict__ w1, const void* __restrict__ w2,
          u16* __restrict__ xn, u16* __restrict__ WT3, u32* __restrict__ flag,
          int nxb)
{
  __shared__ int sh_hits;
  __shared__ u16 tile[64][72];
  if (threadIdx.x == 0) sh_hits = 0;
  __syncthreads();
  {
    const u16* w = (const u16*)w0;
    int h = 0;
    for (int i = threadIdx.x; i < 8192; i += 256)
      if ((w[i] & 0x7F80u) == 0x7F80u) h++;
    if (h) atomicAdd(&sh_hits, h);
  }
  __syncthreads();
  const bool isf32 = (sh_hits > 0);
  const int blk = blockIdx.x;
  const int tid = threadIdx.x;
  if (blk == 0 && tid == 0) *flag = isf32 ? 1000u : 0u;

  if (blk < nxb) {
    // ---- x normalize: 8 elems/thread ----
    long i = ((long)blk * 256 + tid) * 8;
    u16 o[8];
    if (isf32) {
      const float* s = (const float*)xs + i;
      f32x4 a = *(const f32x4*)s;
      f32x4 b = *(const f32x4*)(s + 4);
#pragma unroll
      for (int c = 0; c < 4; ++c) { o[c] = f2bf(a[c]); o[c + 4] = f2bf(b[c]); }
    } else {
      *(uint4*)o = *(const uint4*)((const u16*)xs + i);
    }
    *(uint4*)(xn + i) = *(uint4*)o;
  } else {
    // ---- weight normalize+transpose: t -> (z, by, bx) over (3,16,16) ----
    const int Dd = 1024;
    int t = blk - nxb;
    int z = t >> 8;
    int r = t & 255;
    const int r0 = (r >> 4) * 64, c0 = (r & 15) * 64;
    const void* src = (z == 0) ? w0 : (z == 1) ? w1 : w2;
    u16* out = WT3 + (long)z * Dd * Dd;
#pragma unroll
    for (int p = 0; p < 2; ++p) {
      int v = tid + p * 256;
      int row = v >> 3, c8 = (v & 7) * 8;
      u16 tt[8];
      if (isf32) {
        const float* sp = (const float*)src + (long)(r0 + row) * Dd + c0 + c8;
        f32x4 a = *(const f32x4*)sp;
        f32x4 b = *(const f32x4*)(sp + 4);
#pragma unroll
        for (int c = 0; c < 4; ++c) { tt[c] = f2bf(a[c]); tt[c + 4] = f2bf(b[c]); }
      } else {
        *(uint4*)tt = *(const uint4*)((const u16*)src + (long)(r0 + row) * Dd + c0 + c8);
      }
#pragma unroll
      for (int c = 0; c < 8; ++c) tile[row][c8 + c] = tt[c];
    }
    __syncthreads();
#pragma unroll
    for (int p = 0; p < 2; ++p) {
      int v = tid + p * 256;
      int oc = v >> 3, r8 = (v & 7) * 8;
      union { uint4 q; u16 s[8]; } tt;
#pragma unroll
      for (int c = 0; c < 8; ++c) tt.s[c] = tile[r8 + c][oc];
      *(uint4*)(out + (long)(c0 + oc) * Dd + r0 + r8) = tt.q;
    }
  }
}

// ---------- NT GEMM, 32x32x16 MFMA core ------------------------------------
// A [M,K] bf16, B [N,K] bf16, C [M,N]. LDS XOR-swizzled on the global-read
// side (slot [r][p] holds global chunk p^(r&7)); fragment ds_read_b128 hits
// each bank exactly 2x per phase (hardware minimum).
// Fragment maps: A/B [m=lane&31][k=(lane>>5)*8+j];
// C/D col=lane&31, row=(reg&3)+8*(reg>>2)+4*(lane>>5) (m74/m101-verified).
// MODE 0: bf16 out. MODE 1: f32 out. MODE 2: flag-selected bf16/f32 out.
// trik: K-loop limited to k < m0+BM (PV causal pruning) + longest-first bm.
template <int MODE>
__global__ __launch_bounds__(256, 2)
void gemm_nt(const u16* __restrict__ A, const u16* __restrict__ B, void* __restrict__ Cv,
             const u32* __restrict__ flag,
             int K, int lda, int ldb, int ldc,
             long sA, long sB, long sC, long cOff,
             float scale, int causal, int trik)
{
  int bm = blockIdx.y;
  if (trik) bm = gridDim.y - 1 - bm;   // longest blocks dispatched first
  const int bn = blockIdx.x, bz = blockIdx.z;
  if (causal && bn > bm) return;

  __shared__ u16 As[BM * BK];
  __shared__ u16 Bs[BN * BK];

  A += (long)bz * sA;
  B += (long)bz * sB;

  const int tid  = threadIdx.x;
  const int wid  = tid >> 6;
  const int lane = tid & 63;
  const int l32  = lane & 31;
  const int lh   = lane >> 5;                   // 0..1
  const int srow = lane >> 3;                   // 0..7 (staging row in slab)
  const int swz  = ((lane & 7) ^ srow) * 8;     // swizzled staging col (elems)
  const int m0 = bm * BM, n0 = bn * BN;

  int nk = K / BK;
  if (trik) { int lim = (m0 + BM) / BK; if (lim < nk) nk = lim; }

  f32x16 acc[2][2] = {};

  for (int kt = 0; kt < nk; ++kt) {
    const int k0 = kt * BK;
#pragma unroll
    for (int c = 0; c < 4; ++c) {
      const int rb = wid * 32 + c * 8;          // wave-uniform 8-row slab base
      async_copy16(A + (long)(m0 + rb + srow) * lda + (k0 + swz), As + rb * BK);
      async_copy16(B + (long)(n0 + rb + srow) * ldb + (k0 + swz), Bs + rb * BK);
    }
    __syncthreads();
#pragma unroll
    for (int ks = 0; ks < 4; ++ks) {            // K-steps of 16
      bf16x8 av[2], bv[2];
      const int cb = ((ks * 2 + lh) ^ (lane & 7)) * 8;   // de-swizzled chunk
#pragma unroll
      for (int i = 0; i < 2; ++i) {
        const int Ra = (wid >> 1) * 64 + i * 32 + l32;
        const int Rb = (wid & 1)  * 64 + i * 32 + l32;
        av[i] = *(const bf16x8*)(As + Ra * BK + cb);
        bv[i] = *(const bf16x8*)(Bs + Rb * BK + cb);
      }
#pragma unroll
      for (int mi = 0; mi < 2; ++mi)
#pragma unroll
        for (int ni = 0; ni < 2; ++ni)
          acc[mi][ni] = __builtin_amdgcn_mfma_f32_32x32x16_bf16(av[mi], bv[ni], acc[mi][ni], 0, 0, 0);
    }
    __syncthreads();
  }

  // epilogue
  const int rb0 = m0 + (wid >> 1) * 64;
  const int cb0 = n0 + (wid & 1) * 64;
  const long cbase = (long)bz * sC + cOff;
  const bool f32out = (MODE == 1) || (MODE == 2 && *flag > 32);

#pragma unroll
  for (int mi = 0; mi < 2; ++mi)
#pragma unroll
    for (int ni = 0; ni < 2; ++ni) {
      const int col = cb0 + ni * 32 + l32;
#pragma unroll
      for (int reg = 0; reg < 16; ++reg) {
        const int row = rb0 + mi * 32 + (reg & 3) + 8 * (reg >> 2) + 4 * lh;
        const float v = acc[mi][ni][reg] * scale;
        const long idx = cbase + (long)row * ldc + col;
        if constexpr (MODE == 0) {
          ((u16*)Cv)[idx] = f2bf(v);
        } else if constexpr (MODE == 1) {
          ((float*)Cv)[idx] = v;
        } else {
          if (f32out) ((float*)Cv)[idx] = v;
          else        ((u16*)Cv)[idx]   = f2bf(v);
        }
      }
    }
}

// ---------- bf16 tile transpose: out[c][r] = in[r][c], 64x64 LDS tiles -----
__global__ __launch_bounds__(256)
void transpose_bf16(const u16* __restrict__ in, u16* __restrict__ out,
                    int ldIn, int ldOut, long sIn, long sOut)
{
  __shared__ u16 tile[64][72];
  const int bz = blockIdx.z;
  in  += (long)bz * sIn;
  out += (long)bz * sOut;
  const int r0 = blockIdx.y * 64, c0 = blockIdx.x * 64;
  const int tid = threadIdx.x;
#pragma unroll
  for (int p = 0; p < 2; ++p) {
    int v = tid + p * 256;
    int row = v >> 3, c8 = (v & 7) * 8;
    union { uint4 q; u16 s[8]; } t;
    t.q = *(const uint4*)(in + (long)(r0 + row) * ldIn + c0 + c8);
#pragma unroll
    for (int i = 0; i < 8; ++i) tile[row][c8 + i] = t.s[i];
  }
  __syncthreads();
#pragma unroll
  for (int p = 0; p < 2; ++p) {
    int v = tid + p * 256;
    int oc = v >> 3, r8 = (v & 7) * 8;
    union { uint4 q; u16 s[8]; } t;
#pragma unroll
    for (int i = 0; i < 8; ++i) t.s[i] = tile[r8 + i][oc];
    *(uint4*)(out + (long)(c0 + oc) * ldOut + r0 + r8) = t.q;
  }
}

// ---------- causal softmax, one pass: 256 thr x 8 elems = S ----------------
__global__ __launch_bounds__(256)
void softmax_causal(char* __restrict__ base, long rowStrideB, int modS)
{
  const long r = blockIdx.x;
  const int i = (int)(r % modS);
  float* sc = (float*)(base + r * rowStrideB);
  u16*   pr = (u16*)(base + r * rowStrideB);
  const int n = i + 1;
  const int tid = threadIdx.x;
  const int j0 = tid * 8;
  const int wv = tid >> 6, lane = tid & 63;
  __shared__ float red[4];

  float e[8];
  float m = -3.0e38f;
  if (j0 < n) {
    f32x4 a = *(const f32x4*)(sc + j0);
    f32x4 b = *(const f32x4*)(sc + j0 + 4);
#pragma unroll
    for (int c = 0; c < 4; ++c) { e[c] = a[c]; e[c + 4] = b[c]; }
#pragma unroll
    for (int c = 0; c < 8; ++c) {
      if (j0 + c < n) m = fmaxf(m, e[c]); else e[c] = -3.0e38f;
    }
  } else {
#pragma unroll
    for (int c = 0; c < 8; ++c) e[c] = -3.0e38f;
  }
#pragma unroll
  for (int o = 32; o > 0; o >>= 1) m = fmaxf(m, __shfl_xor(m, o));
  if (lane == 0) red[wv] = m;
  __syncthreads();
  m = fmaxf(fmaxf(red[0], red[1]), fmaxf(red[2], red[3]));
  __syncthreads();

  float s = 0.f;
#pragma unroll
  for (int c = 0; c < 8; ++c) { float x = __expf(e[c] - m); e[c] = x; s += x; }
#pragma unroll
  for (int o = 32; o > 0; o >>= 1) s += __shfl_xor(s, o);
  if (lane == 0) red[wv] = s;
  __syncthreads();
  s = red[0] + red[1] + red[2] + red[3];
  const float inv = 1.0f / s;

  u16 o8[8];
#pragma unroll
  for (int c = 0; c < 8; ++c) o8[c] = f2bf(e[c] * inv);  // masked lanes: exp->0
  *(uint4*)(pr + j0) = *(uint4*)o8;
}

extern "C" void kernel_launch(void* const* d_in, const int* in_sizes, int n_in,
                              void* d_out, int out_size, void* d_ws, size_t ws_size,
                              hipStream_t stream)
{
  (void)in_sizes; (void)n_in; (void)out_size;
  const int Bb = 4, S = 2048, D = 1024, D3 = 3072;
  const long SD = (long)S * D;            // 2,097,152
  const long SS = (long)S * S;            // 4,194,304
  const long N_X = (long)Bb * SD;         // 8,388,608
  const long N_W = (long)D * D;           // 1,048,576

  char* ws = (char*)d_ws;
  size_t off = 0;
  auto take = [&](size_t bytes) -> void* {
    void* p = ws + off;
    off = (off + bytes + 255) & ~((size_t)255);
    return p;
  };

  // ---- common allocations (~22 MB)
  u32* flag = (u32*)take(4096);
  u16* xn   = (u16*)take((size_t)N_X * 2);
  u16* WT3  = (u16*)take((size_t)3 * N_W * 2);   // packed Wq^T|Wk^T|Wv^T
  const size_t off_common = off;

  const size_t needA = off_common + (size_t)(N_X * 3 * 2)      // QKV packed 48 MB
                     + (size_t)(N_X * 2)                       // VT 16 MB
                     + (size_t)(Bb * SS * 4) + 4096;           // scores 64 MB
  const size_t needC = off_common + (size_t)(S * (long)D3 * 2) // QKVb 12 MB
                     + (size_t)(SD * 2)                        // VTb 4 MB
                     + (size_t)(SS * 4) + 4096;                // scb 16 MB

  if (ws_size < needC) {
    zerofill_u16<<<(int)(N_X / 256), 256, 0, stream>>>((u16*)d_out);
    return;
  }

  // ---- fused prep: detect + normalize x + transnorm W (one launch) ----
  const int nxb = (int)(N_X / 2048);   // 4096 x-blocks
  prep<<<nxb + 768, 256, 0, stream>>>(d_in[0], d_in[1], d_in[2], d_in[3],
                                      xn, WT3, flag, nxb);

  const float scl = 0.03125f;  // 1024^-0.5

  if (ws_size >= needA) {
    // ================= Tier A: fully batched (~150 MB) =================
    u16*   QKV = (u16*)take((size_t)N_X * 3 * 2);   // [B*S][3072] = Q|K|V
    u16*   VT  = (u16*)take((size_t)N_X * 2);       // [B][D][S]
    float* sc  = (float*)take((size_t)Bb * SS * 4);

    // fused QKV projection: [8192,1024] @ [3072,1024]^T -> [8192,3072]
    gemm_nt<0><<<dim3(D3 / BN, (int)(N_X / D) / BM, 1), 256, 0, stream>>>(
        xn, WT3, QKV, flag, D, D, D, D3, 0, 0, 0, 0, 1.f, 0, 0);

    // V (cols 2048..3071 of QKV) -> VT per batch
    transpose_bf16<<<dim3(D / 64, S / 64, Bb), 256, 0, stream>>>(
        QKV + 2048, VT, D3, S, (long)S * D3, SD);

    // scores = (Q K^T) * scl, f32, lower-triangle tiles only
    gemm_nt<1><<<dim3(S / BN, S / BM, Bb), 256, 0, stream>>>(
        QKV, QKV + 1024, sc, flag, D, D3, D3, S,
        (long)S * D3, (long)S * D3, SS, 0, scl, 1, 0);

    softmax_causal<<<Bb * S, 256, 0, stream>>>((char*)sc, (long)S * 4, S);

    // out = P @ V (NT vs VT), causal K pruning, dtype-adaptive writeout
    gemm_nt<2><<<dim3(D / BN, S / BM, Bb), 256, 0, stream>>>(
        (u16*)sc, VT, d_out, flag, S, 2 * S, S, D,
        2 * SS, SD, SD, 0, 1.f, 0, 1);
  } else {
    // ================= Tier C: per-batch (~54 MB) =================
    u16*   QKVb = (u16*)take((size_t)S * D3 * 2);
    u16*   VTb  = (u16*)take((size_t)SD * 2);
    float* scb  = (float*)take((size_t)SS * 4);

    for (int b = 0; b < Bb; ++b) {
      gemm_nt<0><<<dim3(D3 / BN, S / BM, 1), 256, 0, stream>>>(
          xn + (long)b * SD, WT3, QKVb, flag, D, D, D, D3, 0, 0, 0, 0, 1.f, 0, 0);

      transpose_bf16<<<dim3(D / 64, S / 64, 1), 256, 0, stream>>>(
          QKVb + 2048, VTb, D3, S, 0, 0);

      gemm_nt<1><<<dim3(S / BN, S / BM, 1), 256, 0, stream>>>(
          QKVb, QKVb + 1024, scb, flag, D, D3, D3, S, 0, 0, 0, 0, scl, 1, 0);

      softmax_causal<<<S, 256, 0, stream>>>((char*)scb, (long)S * 4, S);

      gemm_nt<2><<<dim3(D / BN, S / BM, 1), 256, 0, stream>>>(
          (u16*)scb, VTb, d_out, flag, S, 2 * S, S, D,
          0, 0, 0, (long)b * SD, 1.f, 0, 1);
    }
  }
}

// Round 7
// 264.083 us; speedup vs baseline: 1.0136x; 1.0136x over previous
//
#include <hip/hip_runtime.h>
#include <stdint.h>

typedef unsigned short u16;
typedef unsigned int u32;
typedef __bf16 bf16x8 __attribute__((ext_vector_type(8)));
typedef float f32x4 __attribute__((ext_vector_type(4)));

#define BM 128
#define BN 128
#define BK 64

__device__ __forceinline__ u16 f2bf(float x) {
  union { float f; uint32_t u; } c; c.f = x;
  uint32_t r = (c.u + 0x7FFFu + ((c.u >> 16) & 1u)) >> 16;
  return (u16)r;
}

// async global->LDS, 16B per lane; LDS dest = wave-uniform base + lane*16
__device__ __forceinline__ void async_copy16(const u16* g, u16* l) {
  __builtin_amdgcn_global_load_lds(
      (const __attribute__((address_space(1))) void*)g,
      (__attribute__((address_space(3))) void*)l,
      16, 0, 0);
}

__global__ void zerofill_u16(u16* __restrict__ p) {
  long i = (long)blockIdx.x * 256 + threadIdx.x;
  p[i] = 0;
}

// ---------- fused prep: dtype self-detect + x normalize + W transnorm ------
// Every block samples the SAME first 8192 u16 of Wq: bf16 weights give 0
// exp==0xFF hits (finite values); f32 mantissa halves give ~16 (P(0)~1e-7).
// Identical sample => identical per-block decision, no global dependency.
__global__ __launch_bounds__(256)
void prep(const void* __restrict__ xs, const void* __restrict__ w0,
          const void* __restrict__ w1, const void* __restrict__ w2,
          u16* __restrict__ xn, u16* __restrict__ WT3, u32* __restrict__ flag,
          int nxb)
{
  __shared__ int sh_hits;
  __shared__ u16 tile[64][72];
  if (threadIdx.x == 0) sh_hits = 0;
  __syncthreads();
  {
    const u16* w = (const u16*)w0;
    int h = 0;
    for (int i = threadIdx.x; i < 8192; i += 256)
      if ((w[i] & 0x7F80u) == 0x7F80u) h++;
    if (h) atomicAdd(&sh_hits, h);
  }
  __syncthreads();
  const bool isf32 = (sh_hits > 0);
  const int blk = blockIdx.x;
  const int tid = threadIdx.x;
  if (blk == 0 && tid == 0) *flag = isf32 ? 1000u : 0u;

  if (blk < nxb) {
    long i = ((long)blk * 256 + tid) * 8;
    u16 o[8];
    if (isf32) {
      const float* s = (const float*)xs + i;
      f32x4 a = *(const f32x4*)s;
      f32x4 b = *(const f32x4*)(s + 4);
#pragma unroll
      for (int c = 0; c < 4; ++c) { o[c] = f2bf(a[c]); o[c + 4] = f2bf(b[c]); }
    } else {
      *(uint4*)o = *(const uint4*)((const u16*)xs + i);
    }
    *(uint4*)(xn + i) = *(uint4*)o;
  } else {
    const int Dd = 1024;
    int t = blk - nxb;
    int z = t >> 8;
    int r = t & 255;
    const int r0 = (r >> 4) * 64, c0 = (r & 15) * 64;
    const void* src = (z == 0) ? w0 : (z == 1) ? w1 : w2;
    u16* out = WT3 + (long)z * Dd * Dd;
#pragma unroll
    for (int p = 0; p < 2; ++p) {
      int v = tid + p * 256;
      int row = v >> 3, c8 = (v & 7) * 8;
      u16 tt[8];
      if (isf32) {
        const float* sp = (const float*)src + (long)(r0 + row) * Dd + c0 + c8;
        f32x4 a = *(const f32x4*)sp;
        f32x4 b = *(const f32x4*)(sp + 4);
#pragma unroll
        for (int c = 0; c < 4; ++c) { tt[c] = f2bf(a[c]); tt[c + 4] = f2bf(b[c]); }
      } else {
        *(uint4*)tt = *(const uint4*)((const u16*)src + (long)(r0 + row) * Dd + c0 + c8);
      }
#pragma unroll
      for (int c = 0; c < 8; ++c) tile[row][c8 + c] = tt[c];
    }
    __syncthreads();
#pragma unroll
    for (int p = 0; p < 2; ++p) {
      int v = tid + p * 256;
      int oc = v >> 3, r8 = (v & 7) * 8;
      union { uint4 q; u16 s[8]; } tt;
#pragma unroll
      for (int c = 0; c < 8; ++c) tt.s[c] = tile[r8 + c][oc];
      *(uint4*)(out + (long)(c0 + oc) * Dd + r0 + r8) = tt.q;
    }
  }
}

// ---------- NT GEMM, 16x16x32 MFMA core (r5-verified: 0 conflicts) ---------
// A [M,K] bf16, B [N,K] bf16, C [M,N]. LDS XOR-swizzled on the global-read
// side: slot [r][p] holds global chunk p^(r&7). 16-row fragment geometry =>
// only 2-way bank aliasing (free, m136). DO NOT switch to 32x32 fragments:
// 32 rows x same-chunk reads alias 4-way structurally (r6 regression).
// MODE 0: bf16 out. MODE 1: f32 out. MODE 2: flag-selected bf16/f32 out.
// causal==1: skip bn>bm (2D grid). causal==2: triangular 1D grid (gridDim.x
// = T(n) blocks, decode bm,bn from blockIdx.x). trik: K<m0+BM + longest-first.
template <int MODE>
__global__ __launch_bounds__(256, 2)
void gemm_nt(const u16* __restrict__ A, const u16* __restrict__ B, void* __restrict__ Cv,
             const u32* __restrict__ flag,
             int K, int lda, int ldb, int ldc,
             long sA, long sB, long sC, long cOff,
             float scale, int causal, int trik)
{
  int bm, bn;
  if (causal == 2) {
    int t = blockIdx.x;
    bm = (int)((__fsqrt_rn(8.0f * (float)t + 1.0f) - 1.0f) * 0.5f);
    while ((bm + 1) * (bm + 2) / 2 <= t) ++bm;
    while (bm * (bm + 1) / 2 > t) --bm;
    bn = t - bm * (bm + 1) / 2;
  } else {
    bm = blockIdx.y;
    if (trik) bm = gridDim.y - 1 - bm;   // longest blocks dispatched first
    bn = blockIdx.x;
    if (causal == 1 && bn > bm) return;
  }
  const int bz = blockIdx.z;

  __shared__ u16 As[BM * BK];
  __shared__ u16 Bs[BN * BK];

  A += (long)bz * sA;
  B += (long)bz * sB;

  const int tid  = threadIdx.x;
  const int wid  = tid >> 6;
  const int lane = tid & 63;
  const int l16  = lane & 15;
  const int lk   = lane >> 4;                   // 0..3
  const int srow = lane >> 3;                   // 0..7 (staging row in slab)
  const int swz  = ((lane & 7) ^ srow) * 8;     // swizzled staging col (elems)
  const int m0 = bm * BM, n0 = bn * BN;

  int nk = K / BK;
  if (trik) { int lim = (m0 + BM) / BK; if (lim < nk) nk = lim; }

  f32x4 acc[4][4] = {};

  for (int kt = 0; kt < nk; ++kt) {
    const int k0 = kt * BK;
#pragma unroll
    for (int c = 0; c < 4; ++c) {
      const int rb = wid * 32 + c * 8;          // wave-uniform 8-row slab base
      async_copy16(A + (long)(m0 + rb + srow) * lda + (k0 + swz), As + rb * BK);
      async_copy16(B + (long)(n0 + rb + srow) * ldb + (k0 + swz), Bs + rb * BK);
    }
    __syncthreads();
#pragma unroll
    for (int kh = 0; kh < 2; ++kh) {
      bf16x8 av[4], bv[4];
#pragma unroll
      for (int i = 0; i < 4; ++i) {
        const int Ra = (wid >> 1) * 64 + i * 16 + l16;
        const int Rb = (wid & 1)  * 64 + i * 16 + l16;
        const int ca = ((kh * 4 + lk) ^ (l16 & 7)) * 8;  // de-swizzled chunk
        av[i] = *(const bf16x8*)(As + Ra * BK + ca);
        bv[i] = *(const bf16x8*)(Bs + Rb * BK + ca);
      }
#pragma unroll
      for (int mi = 0; mi < 4; ++mi)
#pragma unroll
        for (int ni = 0; ni < 4; ++ni)
          acc[mi][ni] = __builtin_amdgcn_mfma_f32_16x16x32_bf16(av[mi], bv[ni], acc[mi][ni], 0, 0, 0);
    }
    __syncthreads();
  }

  // C/D layout (m89-verified): col = lane&15, row = (lane>>4)*4 + reg
  const int rb0 = m0 + (wid >> 1) * 64;
  const int cb0 = n0 + (wid & 1) * 64;
  const long cbase = (long)bz * sC + cOff;
  const bool f32out = (MODE == 1) || (MODE == 2 && *flag > 32);

#pragma unroll
  for (int mi = 0; mi < 4; ++mi)
#pragma unroll
    for (int ni = 0; ni < 4; ++ni) {
      const int row = rb0 + mi * 16 + lk * 4;
      const int col = cb0 + ni * 16 + l16;
#pragma unroll
      for (int r = 0; r < 4; ++r) {
        const float v = acc[mi][ni][r] * scale;
        const long idx = cbase + (long)(row + r) * ldc + col;
        if constexpr (MODE == 0) {
          ((u16*)Cv)[idx] = f2bf(v);
        } else if constexpr (MODE == 1) {
          ((float*)Cv)[idx] = v;
        } else {
          if (f32out) ((float*)Cv)[idx] = v;
          else        ((u16*)Cv)[idx]   = f2bf(v);
        }
      }
    }
}

// ---------- bf16 tile transpose: out[c][r] = in[r][c], 64x64 LDS tiles -----
__global__ __launch_bounds__(256)
void transpose_bf16(const u16* __restrict__ in, u16* __restrict__ out,
                    int ldIn, int ldOut, long sIn, long sOut)
{
  __shared__ u16 tile[64][72];
  const int bz = blockIdx.z;
  in  += (long)bz * sIn;
  out += (long)bz * sOut;
  const int r0 = blockIdx.y * 64, c0 = blockIdx.x * 64;
  const int tid = threadIdx.x;
#pragma unroll
  for (int p = 0; p < 2; ++p) {
    int v = tid + p * 256;
    int row = v >> 3, c8 = (v & 7) * 8;
    union { uint4 q; u16 s[8]; } t;
    t.q = *(const uint4*)(in + (long)(r0 + row) * ldIn + c0 + c8);
#pragma unroll
    for (int i = 0; i < 8; ++i) tile[row][c8 + i] = t.s[i];
  }
  __syncthreads();
#pragma unroll
  for (int p = 0; p < 2; ++p) {
    int v = tid + p * 256;
    int oc = v >> 3, r8 = (v & 7) * 8;
    union { uint4 q; u16 s[8]; } t;
#pragma unroll
    for (int i = 0; i < 8; ++i) t.s[i] = tile[r8 + i][oc];
    *(uint4*)(out + (long)(c0 + oc) * ldOut + r0 + r8) = t.q;
  }
}

// ---------- causal softmax, one pass: 256 thr x 8 elems = S ----------------
__global__ __launch_bounds__(256)
void softmax_causal(char* __restrict__ base, long rowStrideB, int modS)
{
  const long r = blockIdx.x;
  const int i = (int)(r % modS);
  float* sc = (float*)(base + r * rowStrideB);
  u16*   pr = (u16*)(base + r * rowStrideB);
  const int n = i + 1;
  const int tid = threadIdx.x;
  const int j0 = tid * 8;
  const int wv = tid >> 6, lane = tid & 63;
  __shared__ float red[4];

  float e[8];
  float m = -3.0e38f;
  if (j0 < n) {
    f32x4 a = *(const f32x4*)(sc + j0);
    f32x4 b = *(const f32x4*)(sc + j0 + 4);
#pragma unroll
    for (int c = 0; c < 4; ++c) { e[c] = a[c]; e[c + 4] = b[c]; }
#pragma unroll
    for (int c = 0; c < 8; ++c) {
      if (j0 + c < n) m = fmaxf(m, e[c]); else e[c] = -3.0e38f;
    }
  } else {
#pragma unroll
    for (int c = 0; c < 8; ++c) e[c] = -3.0e38f;
  }
#pragma unroll
  for (int o = 32; o > 0; o >>= 1) m = fmaxf(m, __shfl_xor(m, o));
  if (lane == 0) red[wv] = m;
  __syncthreads();
  m = fmaxf(fmaxf(red[0], red[1]), fmaxf(red[2], red[3]));
  __syncthreads();

  float s = 0.f;
#pragma unroll
  for (int c = 0; c < 8; ++c) { float x = __expf(e[c] - m); e[c] = x; s += x; }
#pragma unroll
  for (int o = 32; o > 0; o >>= 1) s += __shfl_xor(s, o);
  if (lane == 0) red[wv] = s;
  __syncthreads();
  s = red[0] + red[1] + red[2] + red[3];
  const float inv = 1.0f / s;

  u16 o8[8];
#pragma unroll
  for (int c = 0; c < 8; ++c) o8[c] = f2bf(e[c] * inv);  // masked lanes: exp->0
  *(uint4*)(pr + j0) = *(uint4*)o8;
}

extern "C" void kernel_launch(void* const* d_in, const int* in_sizes, int n_in,
                              void* d_out, int out_size, void* d_ws, size_t ws_size,
                              hipStream_t stream)
{
  (void)in_sizes; (void)n_in; (void)out_size;
  const int Bb = 4, S = 2048, D = 1024, D3 = 3072;
  const long SD = (long)S * D;            // 2,097,152
  const long SS = (long)S * S;            // 4,194,304
  const long N_X = (long)Bb * SD;         // 8,388,608
  const long N_W = (long)D * D;           // 1,048,576
  const int NTRI = 16 * 17 / 2;           // 136 lower-triangle tiles

  char* ws = (char*)d_ws;
  size_t off = 0;
  auto take = [&](size_t bytes) -> void* {
    void* p = ws + off;
    off = (off + bytes + 255) & ~((size_t)255);
    return p;
  };

  // ---- common allocations (~22 MB)
  u32* flag = (u32*)take(4096);
  u16* xn   = (u16*)take((size_t)N_X * 2);
  u16* WT3  = (u16*)take((size_t)3 * N_W * 2);   // packed Wq^T|Wk^T|Wv^T
  const size_t off_common = off;

  const size_t needA = off_common + (size_t)(N_X * 3 * 2)      // QKV packed 48 MB
                     + (size_t)(N_X * 2)                       // VT 16 MB
                     + (size_t)(Bb * SS * 4) + 4096;           // scores 64 MB
  const size_t needC = off_common + (size_t)(S * (long)D3 * 2) // QKVb 12 MB
                     + (size_t)(SD * 2)                        // VTb 4 MB
                     + (size_t)(SS * 4) + 4096;                // scb 16 MB

  if (ws_size < needC) {
    zerofill_u16<<<(int)(N_X / 256), 256, 0, stream>>>((u16*)d_out);
    return;
  }

  // ---- fused prep: detect + normalize x + transnorm W (one launch) ----
  const int nxb = (int)(N_X / 2048);   // 4096 x-blocks
  prep<<<nxb + 768, 256, 0, stream>>>(d_in[0], d_in[1], d_in[2], d_in[3],
                                      xn, WT3, flag, nxb);

  const float scl = 0.03125f;  // 1024^-0.5

  if (ws_size >= needA) {
    // ================= Tier A: fully batched (~150 MB) =================
    u16*   QKV = (u16*)take((size_t)N_X * 3 * 2);   // [B*S][3072] = Q|K|V
    u16*   VT  = (u16*)take((size_t)N_X * 2);       // [B][D][S]
    float* sc  = (float*)take((size_t)Bb * SS * 4);

    // fused QKV projection: [8192,1024] @ [3072,1024]^T -> [8192,3072]
    gemm_nt<0><<<dim3(D3 / BN, (int)(N_X / D) / BM, 1), 256, 0, stream>>>(
        xn, WT3, QKV, flag, D, D, D, D3, 0, 0, 0, 0, 1.f, 0, 0);

    // V (cols 2048..3071 of QKV) -> VT per batch
    transpose_bf16<<<dim3(D / 64, S / 64, Bb), 256, 0, stream>>>(
        QKV + 2048, VT, D3, S, (long)S * D3, SD);

    // scores = (Q K^T) * scl, f32, triangular 1D grid (active tiles only)
    gemm_nt<1><<<dim3(NTRI, 1, Bb), 256, 0, stream>>>(
        QKV, QKV + 1024, sc, flag, D, D3, D3, S,
        (long)S * D3, (long)S * D3, SS, 0, scl, 2, 0);

    softmax_causal<<<Bb * S, 256, 0, stream>>>((char*)sc, (long)S * 4, S);

    // out = P @ V (NT vs VT), causal K pruning, dtype-adaptive writeout
    gemm_nt<2><<<dim3(D / BN, S / BM, Bb), 256, 0, stream>>>(
        (u16*)sc, VT, d_out, flag, S, 2 * S, S, D,
        2 * SS, SD, SD, 0, 1.f, 0, 1);
  } else {
    // ================= Tier C: per-batch (~54 MB) =================
    u16*   QKVb = (u16*)take((size_t)S * D3 * 2);
    u16*   VTb  = (u16*)take((size_t)SD * 2);
    float* scb  = (float*)take((size_t)SS * 4);

    for (int b = 0; b < Bb; ++b) {
      gemm_nt<0><<<dim3(D3 / BN, S / BM, 1), 256, 0, stream>>>(
          xn + (long)b * SD, WT3, QKVb, flag, D, D, D, D3, 0, 0, 0, 0, 1.f, 0, 0);

      transpose_bf16<<<dim3(D / 64, S / 64, 1), 256, 0, stream>>>(
          QKVb + 2048, VTb, D3, S, 0, 0);

      gemm_nt<1><<<dim3(NTRI, 1, 1), 256, 0, stream>>>(
          QKVb, QKVb + 1024, scb, flag, D, D3, D3, S, 0, 0, 0, 0, scl, 2, 0);

      softmax_causal<<<S, 256, 0, stream>>>((char*)scb, (long)S * 4, S);

      gemm_nt<2><<<dim3(D / BN, S / BM, 1), 256, 0, stream>>>(
          (u16*)scb, VTb, d_out, flag, S, 2 * S, S, D,
          0, 0, 0, (long)b * SD, 1.f, 0, 1);
    }
  }
}

// Round 8
// 251.093 us; speedup vs baseline: 1.0660x; 1.0517x over previous
//
#include <hip/hip_runtime.h>
#include <stdint.h>

typedef unsigned short u16;
typedef unsigned int u32;
typedef __bf16 bf16x8 __attribute__((ext_vector_type(8)));
typedef float f32x4 __attribute__((ext_vector_type(4)));

#define BM 128
#define BN 128
#define BK 64

__device__ __forceinline__ u16 f2bf(float x) {
  union { float f; uint32_t u; } c; c.f = x;
  uint32_t r = (c.u + 0x7FFFu + ((c.u >> 16) & 1u)) >> 16;
  return (u16)r;
}
__device__ __forceinline__ float bf2f(u16 v) {
  union { uint32_t u; float f; } c; c.u = ((uint32_t)v) << 16;
  return c.f;
}

// async global->LDS, 16B per lane; LDS dest = wave-uniform base + lane*16
__device__ __forceinline__ void async_copy16(const u16* g, u16* l) {
  __builtin_amdgcn_global_load_lds(
      (const __attribute__((address_space(1))) void*)g,
      (__attribute__((address_space(3))) void*)l,
      16, 0, 0);
}

__global__ void zerofill_u16(u16* __restrict__ p) {
  long i = (long)blockIdx.x * 256 + threadIdx.x;
  p[i] = 0;
}

// ---------- fused prep: dtype self-detect + x normalize + W transnorm + ----
// sigma zero. Every block samples the SAME first 8192 u16 of Wq: bf16
// weights give 0 exp==0xFF hits; f32 mantissa halves give ~16 (P(0)~1e-7).
__global__ __launch_bounds__(256)
void prep(const void* __restrict__ xs, const void* __restrict__ w0,
          const void* __restrict__ w1, const void* __restrict__ w2,
          u16* __restrict__ xn, u16* __restrict__ WT3, u32* __restrict__ flag,
          float* __restrict__ sigma, int nxb)
{
  __shared__ int sh_hits;
  __shared__ u16 tile[64][72];
  if (threadIdx.x == 0) sh_hits = 0;
  __syncthreads();
  {
    const u16* w = (const u16*)w0;
    int h = 0;
    for (int i = threadIdx.x; i < 8192; i += 256)
      if ((w[i] & 0x7F80u) == 0x7F80u) h++;
    if (h) atomicAdd(&sh_hits, h);
  }
  __syncthreads();
  const bool isf32 = (sh_hits > 0);
  const int blk = blockIdx.x;
  const int tid = threadIdx.x;
  if (blk == 0 && tid == 0) *flag = isf32 ? 1000u : 0u;

  if (blk < nxb) {
    long i = ((long)blk * 256 + tid) * 8;
    u16 o[8];
    if (isf32) {
      const float* s = (const float*)xs + i;
      f32x4 a = *(const f32x4*)s;
      f32x4 b = *(const f32x4*)(s + 4);
#pragma unroll
      for (int c = 0; c < 4; ++c) { o[c] = f2bf(a[c]); o[c + 4] = f2bf(b[c]); }
    } else {
      *(uint4*)o = *(const uint4*)((const u16*)xs + i);
    }
    *(uint4*)(xn + i) = *(uint4*)o;
  } else if (blk < nxb + 768) {
    const int Dd = 1024;
    int t = blk - nxb;
    int z = t >> 8;
    int r = t & 255;
    const int r0 = (r >> 4) * 64, c0 = (r & 15) * 64;
    const void* src = (z == 0) ? w0 : (z == 1) ? w1 : w2;
    u16* out = WT3 + (long)z * Dd * Dd;
#pragma unroll
    for (int p = 0; p < 2; ++p) {
      int v = tid + p * 256;
      int row = v >> 3, c8 = (v & 7) * 8;
      u16 tt[8];
      if (isf32) {
        const float* sp = (const float*)src + (long)(r0 + row) * Dd + c0 + c8;
        f32x4 a = *(const f32x4*)sp;
        f32x4 b = *(const f32x4*)(sp + 4);
#pragma unroll
        for (int c = 0; c < 4; ++c) { tt[c] = f2bf(a[c]); tt[c + 4] = f2bf(b[c]); }
      } else {
        *(uint4*)tt = *(const uint4*)((const u16*)src + (long)(r0 + row) * Dd + c0 + c8);
      }
#pragma unroll
      for (int c = 0; c < 8; ++c) tile[row][c8 + c] = tt[c];
    }
    __syncthreads();
#pragma unroll
    for (int p = 0; p < 2; ++p) {
      int v = tid + p * 256;
      int oc = v >> 3, r8 = (v & 7) * 8;
      union { uint4 q; u16 s[8]; } tt;
#pragma unroll
      for (int c = 0; c < 8; ++c) tt.s[c] = tile[r8 + c][oc];
      *(uint4*)(out + (long)(c0 + oc) * Dd + r0 + r8) = tt.q;
    }
  } else {
    // zero sigma: 8 blocks x 256 thr x 4 f32 = 8192
    int t = blk - (nxb + 768);
    *(f32x4*)(sigma + ((long)t * 256 + tid) * 4) = f32x4{0.f, 0.f, 0.f, 0.f};
  }
}

// ---------- NT GEMM, 16x16x32 MFMA core (r5/r7-verified: 0 conflicts) ------
// LDS XOR-swizzled on the global-read side: slot [r][p] holds global chunk
// p^(r&7). 16-row fragment geometry => only 2-way bank aliasing (free).
// DO NOT switch to 32x32 fragments: 4-way structural conflict (r6).
// MODE 0: bf16 out (QKV).
// MODE 2: PV — flag-selected bf16/f32 out, divided by sigma[row].
// MODE 3: scores — triangular 1D grid (blockIdx.x<ntri), writes bf16
//         exp(acc*scale) with causal mask on diagonal tile, atomic per-row
//         sums into sigma. Blocks with blockIdx.x>=ntri do V-transpose.
template <int MODE>
__global__ __launch_bounds__(256, 2)
void gemm_nt(const u16* __restrict__ A, const u16* __restrict__ B, void* __restrict__ Cv,
             const u32* __restrict__ flag, float* __restrict__ sigma, int sigStride,
             int K, int lda, int ldb, int ldc,
             long sA, long sB, long sC, long cOff,
             float scale, int trik, int ntri,
             const u16* __restrict__ vSrc, u16* __restrict__ vtDst,
             long sV, long sVT, int ldV, int ldVT)
{
  __shared__ u16 As[BM * BK];
  __shared__ u16 Bs[BN * BK];
  const int bz = blockIdx.z;
  const int tid = threadIdx.x;

  int bm, bn;
  if constexpr (MODE == 3) {
    if ((int)blockIdx.x >= ntri) {
      // ---- heterogeneous side-block: V 64x64 transpose tile ----
      int t2 = blockIdx.x - ntri;
      const u16* in = vSrc + (long)bz * sV;
      u16* out = vtDst + (long)bz * sVT;
      const int c0 = (t2 & 15) * 64;          // D/64 = 16
      const int r0 = (t2 >> 4) * 64;          // S/64 = 32
      u16 (*tile)[72] = reinterpret_cast<u16(*)[72]>(As);
#pragma unroll
      for (int p = 0; p < 2; ++p) {
        int v = tid + p * 256;
        int row = v >> 3, c8 = (v & 7) * 8;
        union { uint4 q; u16 s[8]; } t;
        t.q = *(const uint4*)(in + (long)(r0 + row) * ldV + c0 + c8);
#pragma unroll
        for (int i = 0; i < 8; ++i) tile[row][c8 + i] = t.s[i];
      }
      __syncthreads();
#pragma unroll
      for (int p = 0; p < 2; ++p) {
        int v = tid + p * 256;
        int oc = v >> 3, r8 = (v & 7) * 8;
        union { uint4 q; u16 s[8]; } t;
#pragma unroll
        for (int i = 0; i < 8; ++i) t.s[i] = tile[r8 + i][oc];
        *(uint4*)(out + (long)(c0 + oc) * ldVT + r0 + r8) = t.q;
      }
      return;
    }
    int t = blockIdx.x;                        // triangular decode
    bm = (int)((__fsqrt_rn(8.0f * (float)t + 1.0f) - 1.0f) * 0.5f);
    while ((bm + 1) * (bm + 2) / 2 <= t) ++bm;
    while (bm * (bm + 1) / 2 > t) --bm;
    bn = t - bm * (bm + 1) / 2;
  } else {
    bm = blockIdx.y;
    if (trik) bm = gridDim.y - 1 - bm;         // longest blocks first
    bn = blockIdx.x;
  }

  A += (long)bz * sA;
  B += (long)bz * sB;

  const int wid  = tid >> 6;
  const int lane = tid & 63;
  const int l16  = lane & 15;
  const int lk   = lane >> 4;                   // 0..3
  const int srow = lane >> 3;                   // 0..7 (staging row in slab)
  const int swz  = ((lane & 7) ^ srow) * 8;     // swizzled staging col
  const int m0 = bm * BM, n0 = bn * BN;

  int nk = K / BK;
  if (trik) { int lim = (m0 + BM) / BK; if (lim < nk) nk = lim; }

  f32x4 acc[4][4] = {};

  for (int kt = 0; kt < nk; ++kt) {
    const int k0 = kt * BK;
#pragma unroll
    for (int c = 0; c < 4; ++c) {
      const int rb = wid * 32 + c * 8;          // wave-uniform 8-row slab base
      async_copy16(A + (long)(m0 + rb + srow) * lda + (k0 + swz), As + rb * BK);
      async_copy16(B + (long)(n0 + rb + srow) * ldb + (k0 + swz), Bs + rb * BK);
    }
    __syncthreads();
#pragma unroll
    for (int kh = 0; kh < 2; ++kh) {
      bf16x8 av[4], bv[4];
#pragma unroll
      for (int i = 0; i < 4; ++i) {
        const int Ra = (wid >> 1) * 64 + i * 16 + l16;
        const int Rb = (wid & 1)  * 64 + i * 16 + l16;
        const int ca = ((kh * 4 + lk) ^ (l16 & 7)) * 8;  // de-swizzled chunk
        av[i] = *(const bf16x8*)(As + Ra * BK + ca);
        bv[i] = *(const bf16x8*)(Bs + Rb * BK + ca);
      }
#pragma unroll
      for (int mi = 0; mi < 4; ++mi)
#pragma unroll
        for (int ni = 0; ni < 4; ++ni)
          acc[mi][ni] = __builtin_amdgcn_mfma_f32_16x16x32_bf16(av[mi], bv[ni], acc[mi][ni], 0, 0, 0);
    }
    __syncthreads();
  }

  // C/D layout (m89-verified): col = lane&15, row = (lane>>4)*4 + reg
  const int rb0 = m0 + (wid >> 1) * 64;
  const int cb0 = n0 + (wid & 1) * 64;
  const long cbase = (long)bz * sC + cOff;

  if constexpr (MODE == 3) {
    // exp + causal mask + bf16 store + atomic row-sums (of the SAME
    // bf16-rounded values PV will consume, so weight errors cancel)
    u16* Cp = (u16*)Cv;
    const bool diag = (bm == bn);
    float* sig = sigma + (long)bz * sigStride;
#pragma unroll
    for (int mi = 0; mi < 4; ++mi)
#pragma unroll
      for (int r = 0; r < 4; ++r) {
        const int row = rb0 + mi * 16 + lk * 4 + r;
        float part = 0.f;
#pragma unroll
        for (int ni = 0; ni < 4; ++ni) {
          const int col = cb0 + ni * 16 + l16;
          float ev = __expf(acc[mi][ni][r] * scale);
          if (diag && col > row) ev = 0.f;
          u16 b = f2bf(ev);
          part += bf2f(b);
          Cp[cbase + (long)row * ldc + col] = b;
        }
#pragma unroll
        for (int o = 1; o < 16; o <<= 1) part += __shfl_xor(part, o);
        if (l16 == 0) atomicAdd(&sig[row], part);
      }
  } else {
    const bool f32out = (MODE == 2) && (*flag > 32);
    const float* sig = (MODE == 2) ? (sigma + (long)bz * sigStride) : nullptr;
#pragma unroll
    for (int mi = 0; mi < 4; ++mi)
#pragma unroll
      for (int r = 0; r < 4; ++r) {
        const int row = rb0 + mi * 16 + lk * 4 + r;
        float rs = scale;
        if constexpr (MODE == 2) rs = 1.0f / sig[row];
#pragma unroll
        for (int ni = 0; ni < 4; ++ni) {
          const int col = cb0 + ni * 16 + l16;
          const float v = acc[mi][ni][r] * rs;
          const long idx = cbase + (long)row * ldc + col;
          if constexpr (MODE == 0) {
            ((u16*)Cv)[idx] = f2bf(v);
          } else {
            if (f32out) ((float*)Cv)[idx] = v;
            else        ((u16*)Cv)[idx]   = f2bf(v);
          }
        }
      }
  }
}

extern "C" void kernel_launch(void* const* d_in, const int* in_sizes, int n_in,
                              void* d_out, int out_size, void* d_ws, size_t ws_size,
                              hipStream_t stream)
{
  (void)in_sizes; (void)n_in; (void)out_size;
  const int Bb = 4, S = 2048, D = 1024, D3 = 3072;
  const long SD  = (long)S * D;           // 2,097,152
  const long SD3 = (long)S * D3;
  const long SS  = (long)S * S;           // 4,194,304
  const long N_X = (long)Bb * SD;         // 8,388,608
  const long N_W = (long)D * D;           // 1,048,576
  const int NTRI = 16 * 17 / 2;           // 136 lower-triangle tiles

  char* ws = (char*)d_ws;
  size_t off = 0;
  auto take = [&](size_t bytes) -> void* {
    void* p = ws + off;
    off = (off + bytes + 255) & ~((size_t)255);
    return p;
  };

  // ---- common allocations (~22 MB)
  u32*   flag  = (u32*)take(4096);
  float* sigma = (float*)take((size_t)Bb * S * 4);  // 32 KB row-sums
  u16*   xn    = (u16*)take((size_t)N_X * 2);
  u16*   WT3   = (u16*)take((size_t)3 * N_W * 2);
  const size_t off_common = off;

  const size_t needA = off_common + (size_t)(N_X * 3 * 2)      // QKV 48 MB
                     + (size_t)(N_X * 2)                       // VT 16 MB
                     + (size_t)(Bb * SS * 2) + 4096;           // E bf16 32 MB
  const size_t needC = off_common + (size_t)(S * (long)D3 * 2) // QKVb 12 MB
                     + (size_t)(SD * 2)                        // VTb 4 MB
                     + (size_t)(SS * 2) + 4096;                // Eb 8 MB

  if (ws_size < needC) {
    zerofill_u16<<<(int)(N_X / 256), 256, 0, stream>>>((u16*)d_out);
    return;
  }

  // ---- fused prep: detect + normalize x + transnorm W + zero sigma ----
  const int nxb = (int)(N_X / 2048);   // 4096 x-blocks
  prep<<<nxb + 768 + 8, 256, 0, stream>>>(d_in[0], d_in[1], d_in[2], d_in[3],
                                          xn, WT3, flag, sigma, nxb);

  const float scl = 0.03125f;  // 1024^-0.5

  if (ws_size >= needA) {
    // ================= Tier A: fully batched (~118 MB) =================
    u16* QKV = (u16*)take((size_t)N_X * 3 * 2);   // [B*S][3072] = Q|K|V
    u16* VT  = (u16*)take((size_t)N_X * 2);       // [B][D][S]
    u16* E   = (u16*)take((size_t)Bb * SS * 2);   // bf16 exp(scores)

    // fused QKV projection: [8192,1024] @ [3072,1024]^T -> [8192,3072]
    gemm_nt<0><<<dim3(D3 / BN, (int)(N_X / D) / BM, 1), 256, 0, stream>>>(
        xn, WT3, QKV, flag, nullptr, 0, D, D, D, D3,
        0, 0, 0, 0, 1.f, 0, 0, nullptr, nullptr, 0, 0, 0, 0);

    // E = exp(Q K^T * scl) bf16 + row-sums sigma; side-blocks transpose V
    gemm_nt<3><<<dim3(NTRI + 512, 1, Bb), 256, 0, stream>>>(
        QKV, QKV + 1024, E, flag, sigma, S, D, D3, D3, S,
        SD3, SD3, SS, 0, scl, 0, NTRI,
        QKV + 2048, VT, SD3, SD, D3, S);

    // out = (E V) / sigma, causal K pruning, dtype-adaptive writeout
    gemm_nt<2><<<dim3(D / BN, S / BM, Bb), 256, 0, stream>>>(
        E, VT, d_out, flag, sigma, S, S, S, S, D,
        SS, SD, SD, 0, 1.f, 1, 0, nullptr, nullptr, 0, 0, 0, 0);
  } else {
    // ================= Tier C: per-batch (~46 MB) =================
    u16* QKVb = (u16*)take((size_t)S * D3 * 2);
    u16* VTb  = (u16*)take((size_t)SD * 2);
    u16* Eb   = (u16*)take((size_t)SS * 2);

    for (int b = 0; b < Bb; ++b) {
      gemm_nt<0><<<dim3(D3 / BN, S / BM, 1), 256, 0, stream>>>(
          xn + (long)b * SD, WT3, QKVb, flag, nullptr, 0, D, D, D, D3,
          0, 0, 0, 0, 1.f, 0, 0, nullptr, nullptr, 0, 0, 0, 0);

      gemm_nt<3><<<dim3(NTRI + 512, 1, 1), 256, 0, stream>>>(
          QKVb, QKVb + 1024, Eb, flag, sigma + (long)b * S, S, D, D3, D3, S,
          0, 0, 0, 0, scl, 0, NTRI,
          QKVb + 2048, VTb, 0, 0, D3, S);

      gemm_nt<2><<<dim3(D / BN, S / BM, 1), 256, 0, stream>>>(
          Eb, VTb, d_out, flag, sigma + (long)b * S, S, S, S, S, D,
          0, 0, 0, (long)b * SD, 1.f, 1, 0, nullptr, nullptr, 0, 0, 0, 0);
    }
  }
}

// Round 9
// 244.721 us; speedup vs baseline: 1.0938x; 1.0260x over previous
//
#include <hip/hip_runtime.h>
#include <stdint.h>

typedef unsigned short u16;
typedef unsigned int u32;
typedef __bf16 bf16x8 __attribute__((ext_vector_type(8)));
typedef float f32x4 __attribute__((ext_vector_type(4)));

#define BM 128
#define BN 128
#define BK 64

__device__ __forceinline__ u16 f2bf(float x) {
  union { float f; uint32_t u; } c; c.f = x;
  uint32_t r = (c.u + 0x7FFFu + ((c.u >> 16) & 1u)) >> 16;
  return (u16)r;
}
__device__ __forceinline__ float bf2f(u16 v) {
  union { uint32_t u; float f; } c; c.u = ((uint32_t)v) << 16;
  return c.f;
}

// async global->LDS, 16B per lane; LDS dest = wave-uniform base + lane*16
__device__ __forceinline__ void async_copy16(const u16* g, u16* l) {
  __builtin_amdgcn_global_load_lds(
      (const __attribute__((address_space(1))) void*)g,
      (__attribute__((address_space(3))) void*)l,
      16, 0, 0);
}

__global__ void zerofill_u16(u16* __restrict__ p) {
  long i = (long)blockIdx.x * 256 + threadIdx.x;
  p[i] = 0;
}

// ---------- fused prep: dtype self-detect + x normalize + W transnorm + ----
// sigma zero. Every block samples the SAME first 8192 u16 of Wq: bf16
// weights give 0 exp==0xFF hits; f32 mantissa halves give ~16 (P(0)~1e-7).
__global__ __launch_bounds__(256)
void prep(const void* __restrict__ xs, const void* __restrict__ w0,
          const void* __restrict__ w1, const void* __restrict__ w2,
          u16* __restrict__ xn, u16* __restrict__ WT3, u32* __restrict__ flag,
          float* __restrict__ sigma, int nxb)
{
  __shared__ int sh_hits;
  __shared__ u16 tile[64][72];
  if (threadIdx.x == 0) sh_hits = 0;
  __syncthreads();
  {
    const u16* w = (const u16*)w0;
    int h = 0;
    for (int i = threadIdx.x; i < 8192; i += 256)
      if ((w[i] & 0x7F80u) == 0x7F80u) h++;
    if (h) atomicAdd(&sh_hits, h);
  }
  __syncthreads();
  const bool isf32 = (sh_hits > 0);
  const int blk = blockIdx.x;
  const int tid = threadIdx.x;
  if (blk == 0 && tid == 0) *flag = isf32 ? 1000u : 0u;

  if (blk < nxb) {
    long i = ((long)blk * 256 + tid) * 8;
    u16 o[8];
    if (isf32) {
      const float* s = (const float*)xs + i;
      f32x4 a = *(const f32x4*)s;
      f32x4 b = *(const f32x4*)(s + 4);
#pragma unroll
      for (int c = 0; c < 4; ++c) { o[c] = f2bf(a[c]); o[c + 4] = f2bf(b[c]); }
    } else {
      *(uint4*)o = *(const uint4*)((const u16*)xs + i);
    }
    *(uint4*)(xn + i) = *(uint4*)o;
  } else if (blk < nxb + 768) {
    const int Dd = 1024;
    int t = blk - nxb;
    int z = t >> 8;
    int r = t & 255;
    const int r0 = (r >> 4) * 64, c0 = (r & 15) * 64;
    const void* src = (z == 0) ? w0 : (z == 1) ? w1 : w2;
    u16* out = WT3 + (long)z * Dd * Dd;
#pragma unroll
    for (int p = 0; p < 2; ++p) {
      int v = tid + p * 256;
      int row = v >> 3, c8 = (v & 7) * 8;
      u16 tt[8];
      if (isf32) {
        const float* sp = (const float*)src + (long)(r0 + row) * Dd + c0 + c8;
        f32x4 a = *(const f32x4*)sp;
        f32x4 b = *(const f32x4*)(sp + 4);
#pragma unroll
        for (int c = 0; c < 4; ++c) { tt[c] = f2bf(a[c]); tt[c + 4] = f2bf(b[c]); }
      } else {
        *(uint4*)tt = *(const uint4*)((const u16*)src + (long)(r0 + row) * Dd + c0 + c8);
      }
#pragma unroll
      for (int c = 0; c < 8; ++c) tile[row][c8 + c] = tt[c];
    }
    __syncthreads();
#pragma unroll
    for (int p = 0; p < 2; ++p) {
      int v = tid + p * 256;
      int oc = v >> 3, r8 = (v & 7) * 8;
      union { uint4 q; u16 s[8]; } tt;
#pragma unroll
      for (int c = 0; c < 8; ++c) tt.s[c] = tile[r8 + c][oc];
      *(uint4*)(out + (long)(c0 + oc) * Dd + r0 + r8) = tt.q;
    }
  } else {
    int t = blk - (nxb + 768);
    *(f32x4*)(sigma + ((long)t * 256 + tid) * 4) = f32x4{0.f, 0.f, 0.f, 0.f};
  }
}

// ---------- NT GEMM, 16x16x32 MFMA core (r5/r7-verified: 0 conflicts) ------
// LDS XOR-swizzled on the global-read side: slot [r][p] holds global chunk
// p^(r&7). 16-row fragment geometry => only 2-way bank aliasing (free).
// DO NOT switch to 32x32 fragments: 4-way structural conflict (r6).
// __launch_bounds__(256,4): 32KB LDS x4 = 128KB <= 160KB; 64 arch + 64 acc
// VGPR = 128 unified -> 4 waves/SIMD. Doubles staging-latency overlap (r8:
// scores dispatch was latency-bound at 12% MfmaUtil, 19% occupancy).
// MODE 0: bf16 out (QKV).
// MODE 2: PV — flag-selected bf16/f32 out, divided by sigma[row].
// MODE 3: scores — supertile-ordered triangular grid (blockIdx.x<ntri):
//         4x4-tile supertiles so co-resident blocks share <=4 Q + <=4 K
//         tiles (4MB, fits one XCD L2). Writes bf16 exp(acc*scale), causal
//         mask on diagonal tile, atomic row-sums. blockIdx.x>=ntri: V-transpose.
template <int MODE>
__global__ __launch_bounds__(256, 4)
void gemm_nt(const u16* __restrict__ A, const u16* __restrict__ B, void* __restrict__ Cv,
             const u32* __restrict__ flag, float* __restrict__ sigma, int sigStride,
             int K, int lda, int ldb, int ldc,
             long sA, long sB, long sC, long cOff,
             float scale, int trik, int ntri,
             const u16* __restrict__ vSrc, u16* __restrict__ vtDst,
             long sV, long sVT, int ldV, int ldVT)
{
  __shared__ u16 As[BM * BK];
  __shared__ u16 Bs[BN * BK];
  const int bz = blockIdx.z;
  const int tid = threadIdx.x;

  int bm, bn;
  if constexpr (MODE == 3) {
    if ((int)blockIdx.x >= ntri) {
      // ---- heterogeneous side-block: V 64x64 transpose tile ----
      int t2 = blockIdx.x - ntri;
      const u16* in = vSrc + (long)bz * sV;
      u16* out = vtDst + (long)bz * sVT;
      const int c0 = (t2 & 15) * 64;          // D/64 = 16
      const int r0 = (t2 >> 4) * 64;          // S/64 = 32
      u16 (*tile)[72] = reinterpret_cast<u16(*)[72]>(As);
#pragma unroll
      for (int p = 0; p < 2; ++p) {
        int v = tid + p * 256;
        int row = v >> 3, c8 = (v & 7) * 8;
        union { uint4 q; u16 s[8]; } t;
        t.q = *(const uint4*)(in + (long)(r0 + row) * ldV + c0 + c8);
#pragma unroll
        for (int i = 0; i < 8; ++i) tile[row][c8 + i] = t.s[i];
      }
      __syncthreads();
#pragma unroll
      for (int p = 0; p < 2; ++p) {
        int v = tid + p * 256;
        int oc = v >> 3, r8 = (v & 7) * 8;
        union { uint4 q; u16 s[8]; } t;
#pragma unroll
        for (int i = 0; i < 8; ++i) t.s[i] = tile[r8 + i][oc];
        *(uint4*)(out + (long)(c0 + oc) * ldVT + r0 + r8) = t.q;
      }
      return;
    }
    // supertile-ordered triangle decode (16x16 tiles, 4x4 supertiles)
    {
      const int t = blockIdx.x;
      const int cum[11] = {0, 10, 26, 36, 52, 68, 78, 94, 110, 126, 136};
      const int ssm[10] = {0, 1, 1, 2, 2, 2, 3, 3, 3, 3};
      const int ssn[10] = {0, 0, 1, 0, 1, 2, 0, 1, 2, 3};
      int s = 0;
      while (cum[s + 1] <= t) ++s;
      const int l = t - cum[s];
      const int sm = ssm[s], sn = ssn[s];
      int tm, tn;
      if (sm == sn) {                 // diagonal supertile: triangular 10
        tm = 0;
        while ((tm + 1) * (tm + 2) / 2 <= l) ++tm;
        tn = l - tm * (tm + 1) / 2;
      } else { tm = l >> 2; tn = l & 3; }
      bm = sm * 4 + tm;
      bn = sn * 4 + tn;
    }
  } else {
    bm = blockIdx.y;
    if (trik) bm = gridDim.y - 1 - bm;         // longest blocks first
    bn = blockIdx.x;
  }

  A += (long)bz * sA;
  B += (long)bz * sB;

  const int wid  = tid >> 6;
  const int lane = tid & 63;
  const int l16  = lane & 15;
  const int lk   = lane >> 4;                   // 0..3
  const int srow = lane >> 3;                   // 0..7 (staging row in slab)
  const int swz  = ((lane & 7) ^ srow) * 8;     // swizzled staging col
  const int m0 = bm * BM, n0 = bn * BN;

  int nk = K / BK;
  if (trik) { int lim = (m0 + BM) / BK; if (lim < nk) nk = lim; }

  f32x4 acc[4][4] = {};

  for (int kt = 0; kt < nk; ++kt) {
    const int k0 = kt * BK;
#pragma unroll
    for (int c = 0; c < 4; ++c) {
      const int rb = wid * 32 + c * 8;          // wave-uniform 8-row slab base
      async_copy16(A + (long)(m0 + rb + srow) * lda + (k0 + swz), As + rb * BK);
      async_copy16(B + (long)(n0 + rb + srow) * ldb + (k0 + swz), Bs + rb * BK);
    }
    __syncthreads();
#pragma unroll
    for (int kh = 0; kh < 2; ++kh) {
      bf16x8 av[4], bv[4];
#pragma unroll
      for (int i = 0; i < 4; ++i) {
        const int Ra = (wid >> 1) * 64 + i * 16 + l16;
        const int Rb = (wid & 1)  * 64 + i * 16 + l16;
        const int ca = ((kh * 4 + lk) ^ (l16 & 7)) * 8;  // de-swizzled chunk
        av[i] = *(const bf16x8*)(As + Ra * BK + ca);
        bv[i] = *(const bf16x8*)(Bs + Rb * BK + ca);
      }
#pragma unroll
      for (int mi = 0; mi < 4; ++mi)
#pragma unroll
        for (int ni = 0; ni < 4; ++ni)
          acc[mi][ni] = __builtin_amdgcn_mfma_f32_16x16x32_bf16(av[mi], bv[ni], acc[mi][ni], 0, 0, 0);
    }
    __syncthreads();
  }

  // C/D layout (m89-verified): col = lane&15, row = (lane>>4)*4 + reg
  const int rb0 = m0 + (wid >> 1) * 64;
  const int cb0 = n0 + (wid & 1) * 64;
  const long cbase = (long)bz * sC + cOff;

  if constexpr (MODE == 3) {
    // exp + causal mask + bf16 store + atomic row-sums (of the SAME
    // bf16-rounded values PV will consume, so weight errors cancel)
    u16* Cp = (u16*)Cv;
    const bool diag = (bm == bn);
    float* sig = sigma + (long)bz * sigStride;
#pragma unroll
    for (int mi = 0; mi < 4; ++mi)
#pragma unroll
      for (int r = 0; r < 4; ++r) {
        const int row = rb0 + mi * 16 + lk * 4 + r;
        float part = 0.f;
#pragma unroll
        for (int ni = 0; ni < 4; ++ni) {
          const int col = cb0 + ni * 16 + l16;
          float ev = __expf(acc[mi][ni][r] * scale);
          if (diag && col > row) ev = 0.f;
          u16 b = f2bf(ev);
          part += bf2f(b);
          Cp[cbase + (long)row * ldc + col] = b;
        }
#pragma unroll
        for (int o = 1; o < 16; o <<= 1) part += __shfl_xor(part, o);
        if (l16 == 0) atomicAdd(&sig[row], part);
      }
  } else {
    const bool f32out = (MODE == 2) && (*flag > 32);
    const float* sig = (MODE == 2) ? (sigma + (long)bz * sigStride) : nullptr;
#pragma unroll
    for (int mi = 0; mi < 4; ++mi)
#pragma unroll
      for (int r = 0; r < 4; ++r) {
        const int row = rb0 + mi * 16 + lk * 4 + r;
        float rs = scale;
        if constexpr (MODE == 2) rs = 1.0f / sig[row];
#pragma unroll
        for (int ni = 0; ni < 4; ++ni) {
          const int col = cb0 + ni * 16 + l16;
          const float v = acc[mi][ni][r] * rs;
          const long idx = cbase + (long)row * ldc + col;
          if constexpr (MODE == 0) {
            ((u16*)Cv)[idx] = f2bf(v);
          } else {
            if (f32out) ((float*)Cv)[idx] = v;
            else        ((u16*)Cv)[idx]   = f2bf(v);
          }
        }
      }
  }
}

extern "C" void kernel_launch(void* const* d_in, const int* in_sizes, int n_in,
                              void* d_out, int out_size, void* d_ws, size_t ws_size,
                              hipStream_t stream)
{
  (void)in_sizes; (void)n_in; (void)out_size;
  const int Bb = 4, S = 2048, D = 1024, D3 = 3072;
  const long SD  = (long)S * D;           // 2,097,152
  const long SD3 = (long)S * D3;
  const long SS  = (long)S * S;           // 4,194,304
  const long N_X = (long)Bb * SD;         // 8,388,608
  const long N_W = (long)D * D;           // 1,048,576
  const int NTRI = 16 * 17 / 2;           // 136 lower-triangle tiles

  char* ws = (char*)d_ws;
  size_t off = 0;
  auto take = [&](size_t bytes) -> void* {
    void* p = ws + off;
    off = (off + bytes + 255) & ~((size_t)255);
    return p;
  };

  // ---- common allocations (~22 MB)
  u32*   flag  = (u32*)take(4096);
  float* sigma = (float*)take((size_t)Bb * S * 4);  // 32 KB row-sums
  u16*   xn    = (u16*)take((size_t)N_X * 2);
  u16*   WT3   = (u16*)take((size_t)3 * N_W * 2);
  const size_t off_common = off;

  const size_t needA = off_common + (size_t)(N_X * 3 * 2)      // QKV 48 MB
                     + (size_t)(N_X * 2)                       // VT 16 MB
                     + (size_t)(Bb * SS * 2) + 4096;           // E bf16 32 MB
  const size_t needC = off_common + (size_t)(S * (long)D3 * 2) // QKVb 12 MB
                     + (size_t)(SD * 2)                        // VTb 4 MB
                     + (size_t)(SS * 2) + 4096;                // Eb 8 MB

  if (ws_size < needC) {
    zerofill_u16<<<(int)(N_X / 256), 256, 0, stream>>>((u16*)d_out);
    return;
  }

  // ---- fused prep: detect + normalize x + transnorm W + zero sigma ----
  const int nxb = (int)(N_X / 2048);   // 4096 x-blocks
  prep<<<nxb + 768 + 8, 256, 0, stream>>>(d_in[0], d_in[1], d_in[2], d_in[3],
                                          xn, WT3, flag, sigma, nxb);

  const float scl = 0.03125f;  // 1024^-0.5

  if (ws_size >= needA) {
    // ================= Tier A: fully batched (~118 MB) =================
    u16* QKV = (u16*)take((size_t)N_X * 3 * 2);   // [B*S][3072] = Q|K|V
    u16* VT  = (u16*)take((size_t)N_X * 2);       // [B][D][S]
    u16* E   = (u16*)take((size_t)Bb * SS * 2);   // bf16 exp(scores)

    // fused QKV projection: [8192,1024] @ [3072,1024]^T -> [8192,3072]
    gemm_nt<0><<<dim3(D3 / BN, (int)(N_X / D) / BM, 1), 256, 0, stream>>>(
        xn, WT3, QKV, flag, nullptr, 0, D, D, D, D3,
        0, 0, 0, 0, 1.f, 0, 0, nullptr, nullptr, 0, 0, 0, 0);

    // E = exp(Q K^T * scl) bf16 + row-sums sigma; side-blocks transpose V
    gemm_nt<3><<<dim3(NTRI + 512, 1, Bb), 256, 0, stream>>>(
        QKV, QKV + 1024, E, flag, sigma, S, D, D3, D3, S,
        SD3, SD3, SS, 0, scl, 0, NTRI,
        QKV + 2048, VT, SD3, SD, D3, S);

    // out = (E V) / sigma, causal K pruning, dtype-adaptive writeout
    gemm_nt<2><<<dim3(D / BN, S / BM, Bb), 256, 0, stream>>>(
        E, VT, d_out, flag, sigma, S, S, S, S, D,
        SS, SD, SD, 0, 1.f, 1, 0, nullptr, nullptr, 0, 0, 0, 0);
  } else {
    // ================= Tier C: per-batch (~46 MB) =================
    u16* QKVb = (u16*)take((size_t)S * D3 * 2);
    u16* VTb  = (u16*)take((size_t)SD * 2);
    u16* Eb   = (u16*)take((size_t)SS * 2);

    for (int b = 0; b < Bb; ++b) {
      gemm_nt<0><<<dim3(D3 / BN, S / BM, 1), 256, 0, stream>>>(
          xn + (long)b * SD, WT3, QKVb, flag, nullptr, 0, D, D, D, D3,
          0, 0, 0, 0, 1.f, 0, 0, nullptr, nullptr, 0, 0, 0, 0);

      gemm_nt<3><<<dim3(NTRI + 512, 1, 1), 256, 0, stream>>>(
          QKVb, QKVb + 1024, Eb, flag, sigma + (long)b * S, S, D, D3, D3, S,
          0, 0, 0, 0, scl, 0, NTRI,
          QKVb + 2048, VTb, 0, 0, D3, S);

      gemm_nt<2><<<dim3(D / BN, S / BM, 1), 256, 0, stream>>>(
          Eb, VTb, d_out, flag, sigma + (long)b * S, S, S, S, S, D,
          0, 0, 0, (long)b * SD, 1.f, 1, 0, nullptr, nullptr, 0, 0, 0, 0);
    }
  }
}